// Round 6
// baseline (481.894 us; speedup 1.0000x reference)
//
#include <hip/hip_runtime.h>

// SelectiveAttnMLA on MI355X (gfx950).
// B=4 S=2048 Hq=16 G=4 D=192 DV=128 BLK=64 NB=32 TOPK=16, out fp32 (8192x2048).
//
// R9: LDS-amplification fix. Analysis across R4/R6/R8 (170/184/212us) shows the
//     LDS pipe is the shared bottleneck: 4 waves each re-read the whole 40KB
//     K/V tile per iteration (~95us of LDS-unit time). Now 2 waves x 32
//     queries each (128 threads): every ds_read_b128 of K/V (A-operands)
//     feeds TWO 16-query tiles (fused QK, fused PV) -> LDS reads halved per
//     query. Schedule (2 barriers/iter, full latency cover, T14 V-detour):
//       QK -> lgkm0+bar(A) -> stageK(nxt) async16 + loadV(nxt)->regs
//          -> softmax x2 + P-exchange x2 -> fused PV (reads sh_v)
//          -> lgkm0+vmcnt0+bar(B)  [K/V(nxt) covered by softmax+PV]
//          -> ds_write V(nxt)->sh_v
//     LDS 40960B -> 4 blocks/CU; VGPR ~200 (NO launch_bounds cap - R7 spill).

typedef __attribute__((ext_vector_type(8))) _Float16 half8;
typedef __attribute__((ext_vector_type(4))) float f32x4;
typedef __attribute__((ext_vector_type(4))) unsigned int u32x4;

__device__ __forceinline__ half8 cvt8(const float4* p) {
  float4 a = p[0], b = p[1];
  half8 r;
  r[0] = (_Float16)a.x; r[1] = (_Float16)a.y; r[2] = (_Float16)a.z; r[3] = (_Float16)a.w;
  r[4] = (_Float16)b.x; r[5] = (_Float16)b.y; r[6] = (_Float16)b.z; r[7] = (_Float16)b.w;
  return r;
}

__device__ __forceinline__ half8 cvt8s(const float4* p, float s) {
  float4 a = p[0], b = p[1];
  half8 r;
  r[0] = (_Float16)(a.x * s); r[1] = (_Float16)(a.y * s);
  r[2] = (_Float16)(a.z * s); r[3] = (_Float16)(a.w * s);
  r[4] = (_Float16)(b.x * s); r[5] = (_Float16)(b.y * s);
  r[6] = (_Float16)(b.z * s); r[7] = (_Float16)(b.w * s);
  return r;
}

__device__ __forceinline__ void async16(const void* g, void* l) {
  __builtin_amdgcn_global_load_lds(
      (const __attribute__((address_space(1))) void*)g,
      (__attribute__((address_space(3))) void*)l, 16, 0, 0);
}

__device__ __forceinline__ f32x4 vmax4(f32x4 a, f32x4 b) {
  f32x4 r;
  r[0] = fmaxf(a[0], b[0]); r[1] = fmaxf(a[1], b[1]);
  r[2] = fmaxf(a[2], b[2]); r[3] = fmaxf(a[3], b[3]);
  return r;
}

// ---------------- fused K/V fragment prepass (unchanged) ----------------
__global__ __launch_bounds__(256) void kv_prep(const float* __restrict__ k,
                                               const float* __restrict__ v,
                                               _Float16* __restrict__ kf,
                                               _Float16* __restrict__ vf) {
  __shared__ float lb[64 * 196];      // K phase: [64][196]; V phase: [64][132]
  int blk = blockIdx.x;               // (b*16+h)*32 + kb
  int bh = blk >> 5, kb = blk & 31;
  int b = bh >> 4, h = bh & 15;
  int tid = threadIdx.x;

  // ---- K: load 64 rows x 192 f32, coalesced ----
  const float* ksrc = k + ((long)(b * 2048 + kb * 64) * 16 + h) * 192;
#pragma unroll
  for (int it = 0; it < 12; ++it) {
    int idx = it * 256 + tid;         // 3072 float4
    int kk = idx / 48, c4 = idx - kk * 48;
    *(float4*)(&lb[kk * 196 + c4 * 4]) = *(const float4*)(ksrc + (long)kk * 3072 + c4 * 4);
  }
  __syncthreads();
  _Float16* kdst = kf + (long)blk * 12288;
#pragma unroll
  for (int it = 0; it < 6; ++it) {
    int oct = it * 256 + tid;         // 1536 octets
    int frag = oct >> 6, lane = oct & 63;
    int ntile = frag / 6, kc = frag - ntile * 6;
    int lm = lane & 15;
    // permuted row: stored slot (ntile, lm) <- actual key (lm>>2)*16 + ntile*4 + (lm&3)
    int n = ((lm >> 2) << 4) + ntile * 4 + (lm & 3);
    int d = kc * 32 + ((lane >> 4) << 3);
    *(half8*)(kdst + (long)oct * 8) = cvt8((const float4*)(&lb[n * 196 + d]));
  }
  __syncthreads();

  // ---- V: load 64 rows x 128 f32, coalesced; emit transposed frags ----
  const float* vsrc = v + ((long)(b * 2048 + kb * 64) * 16 + h) * 128;
#pragma unroll
  for (int it = 0; it < 8; ++it) {
    int idx = it * 256 + tid;         // 2048 float4
    int kk = idx >> 5, c4 = idx & 31;
    *(float4*)(&lb[kk * 132 + c4 * 4]) = *(const float4*)(vsrc + (long)kk * 2048 + c4 * 4);
  }
  __syncthreads();
  _Float16* vdst = vf + (long)blk * 8192;
#pragma unroll
  for (int it = 0; it < 4; ++it) {
    int oct = it * 256 + tid;         // 1024 octets
    int frag = oct >> 6, lane = oct & 63;
    int n0 = frag >> 1, kc = frag & 1;
    int dv = n0 * 16 + (lane & 15);
    int kbase = kc * 32 + ((lane >> 4) << 3);
    half8 o;
#pragma unroll
    for (int j = 0; j < 8; ++j) o[j] = (_Float16)lb[(kbase + j) * 132 + dv];
    *(half8*)(vdst + (long)oct * 8) = o;
  }
}

// ---------------- main attention: 2 waves x 32 queries, fused A-operand reuse ----------------
__global__ __launch_bounds__(128) void attn_main(const float* __restrict__ q,
                                                 const int* __restrict__ idx,
                                                 const _Float16* __restrict__ kf,
                                                 const _Float16* __restrict__ vf,
                                                 float* __restrict__ out) {
  constexpr float SCL = 0.07216878364870322f * 1.4426950408889634f;  // sm_scale*log2e
  int id = (int)blockIdx.x;
  int qb = 31 - (id >> 6);            // qb swizzle: CU gets mixed qb, fixed (b,h)
  int h = id & 15, b = (id >> 4) & 3, g = h >> 2;
  int tid = threadIdx.x;
  int w = tid >> 6, L = tid & 63;
  int Lm = L & 15, Lq = L >> 4;
  int qoff = w * 32;                  // wave's first query row (block-relative)
  int t0 = b * 2048 + qb * 64;

  __shared__ __align__(16) char sh_k[24576];   // K frags (24 x 1KB channels)
  __shared__ __align__(16) char sh_v[16384];   // V frags (16 x 1KB channels) = 40960B

  const char* kfb = (const char*)(kf + (long)((b * 16 + h) * 32) * 12288);
  const _Float16* vfb = vf + (long)((b * 16 + h) * 32) * 8192;

  auto stageK = [&](int kb) {
#pragma unroll
    for (int c = 0; c < 12; ++c) {
      int ch = w + c * 2;
      async16(kfb + (long)kb * 24576 + ch * 1024 + L * 16, sh_k + ch * 1024);
    }
  };

  half8 vreg[8];                      // V(nxt) detour: regs now, LDS after bar(B)
  auto loadVreg = [&](int kb) {
    const half8* vg = (const half8*)(vfb + (long)kb * 8192);
#pragma unroll
    for (int c = 0; c < 8; ++c) vreg[c] = vg[(w + c * 2) * 64 + L];
  };
  auto writeV = [&]() {
#pragma unroll
    for (int c = 0; c < 8; ++c)
      *(half8*)(sh_v + (w + c * 2) * 1024 + L * 16) = vreg[c];
  };

  stageK(0);                          // block 0 always selected
  loadVreg(0);

  // Q as B-operand, two 16-query tiles per wave: rows qoff + j*16 + Lm
  half8 qa[2][6];
#pragma unroll
  for (int j = 0; j < 2; ++j) {
    const float* qrow = q + ((long)(t0 + qoff + j * 16 + Lm) * 16 + h) * 192;
#pragma unroll
    for (int c = 0; c < 6; ++c) qa[j][c] = cvt8s((const float4*)(qrow + c * 32 + Lq * 8), SCL);
  }

  // selection masks: lane L reads the 16 picks of block-row L (covers all 64 rows)
  unsigned rm = 0;
  {
    const int4* ip = (const int4*)(idx + ((long)(t0 + L) * 4 + g) * 16);
#pragma unroll
    for (int u = 0; u < 4; ++u) {
      int4 iv = ip[u];
      rm |= (1u << iv.x) | (1u << iv.y) | (1u << iv.z) | (1u << iv.w);
    }
  }
  unsigned bm = rm;
#pragma unroll
  for (int o = 1; o < 64; o <<= 1) bm |= __shfl_xor(bm, o, 64);   // 64-row union
  unsigned mrow[2];
#pragma unroll
  for (int j = 0; j < 2; ++j) mrow[j] = __shfl(rm, qoff + j * 16 + Lm, 64);
  unsigned bmask = bm & ((2u << qb) - 1);   // bits 0..qb (qb=31 wraps to all-ones)

  // prologue drain: K(0) landed (all waves after barrier), V(0) -> LDS
  asm volatile("s_waitcnt vmcnt(0)" ::: "memory");
  writeV();
  asm volatile("s_waitcnt lgkmcnt(0)\n\ts_barrier" ::: "memory");

  f32x4 Oacc[2][8];                   // per tile: row = dv (Lq*4+i), col = q (Lm)
#pragma unroll
  for (int j = 0; j < 2; ++j)
#pragma unroll
    for (int n0 = 0; n0 < 8; ++n0) Oacc[j][n0] = (f32x4){0.f, 0.f, 0.f, 0.f};
  float m_i[2] = {-1e30f, -1e30f}, l_i[2] = {0.f, 0.f};

  unsigned rem = bmask;               // bit 0 always set
  int kb = 0;

  for (;;) {
    rem &= rem - 1;
    int nxt = rem ? (int)__builtin_ctz(rem) : -1;

    // ---- fused QK^T: each K fragment feeds both q-tiles ----
    const half8* lkf = (const half8*)sh_k;
    f32x4 S[2][4];
#pragma unroll
    for (int j = 0; j < 2; ++j)
#pragma unroll
      for (int nt = 0; nt < 4; ++nt) S[j][nt] = (f32x4){0.f, 0.f, 0.f, 0.f};
    __builtin_amdgcn_s_setprio(1);
#pragma unroll
    for (int nt = 0; nt < 4; ++nt)
#pragma unroll
      for (int c = 0; c < 6; ++c) {
        half8 ka = lkf[(nt * 6 + c) * 64 + L];
        S[0][nt] = __builtin_amdgcn_mfma_f32_16x16x32_f16(ka, qa[0][c], S[0][nt], 0, 0, 0);
        S[1][nt] = __builtin_amdgcn_mfma_f32_16x16x32_f16(ka, qa[1][c], S[1][nt], 0, 0, 0);
      }
    __builtin_amdgcn_s_setprio(0);

    // (A) K reads retired block-wide; prev V writes visible -> sh_k writable
    asm volatile("s_waitcnt lgkmcnt(0)\n\ts_barrier" ::: "memory");
    if (nxt >= 0) {
      stageK(nxt);                    // 12 async16, covered by softmax+PV
      loadVreg(nxt);                  // 8 loads, covered likewise
    }

    // ---- softmax + P-exchange per tile ----
    half8 pfr[2][2];
#pragma unroll
    for (int j = 0; j < 2; ++j) {
      float p[4][4];
      float msel = ((mrow[j] >> kb) & 1u) ? 1.0f : 0.0f;
      if (kb != qb) {
        // selection via 0/1 multiply; inflated row-max is exact (shift-invariance)
        f32x4 t = vmax4(vmax4(S[j][0], S[j][1]), vmax4(S[j][2], S[j][3]));
        float rmax = fmaxf(fmaxf(t[0], t[1]), fmaxf(t[2], t[3]));
        rmax = fmaxf(rmax, __shfl_xor(rmax, 16));
        rmax = fmaxf(rmax, __shfl_xor(rmax, 32));
        if (__any(rmax > m_i[j])) {
          float mn = fmaxf(m_i[j], rmax);
          float av = __builtin_amdgcn_exp2f(m_i[j] - mn);
          m_i[j] = mn;
          l_i[j] *= av;
#pragma unroll
          for (int n0 = 0; n0 < 8; ++n0) Oacc[j][n0] *= av;
        }
        float ps[4];
#pragma unroll
        for (int nt = 0; nt < 4; ++nt) {
          float s0 = 0.f, s1 = 0.f;
#pragma unroll
          for (int i = 0; i < 4; i += 2) {
            float a = __builtin_amdgcn_exp2f(S[j][nt][i] - m_i[j]) * msel;
            float c = __builtin_amdgcn_exp2f(S[j][nt][i + 1] - m_i[j]) * msel;
            p[nt][i] = a; p[nt][i + 1] = c;
            s0 += a; s1 += c;
          }
          ps[nt] = s0 + s1;
        }
        float psum = (ps[0] + ps[1]) + (ps[2] + ps[3]);
        psum += __shfl_xor(psum, 16);
        psum += __shfl_xor(psum, 32);
        l_i[j] += psum;
      } else {
        // diagonal block: per-element causal+selection masking
        int qrow = qoff + j * 16 + Lm;
        float sc[4][4];
        float rmax = -1e30f;
#pragma unroll
        for (int nt = 0; nt < 4; ++nt)
#pragma unroll
          for (int i = 0; i < 4; ++i) {
            int key = Lq * 16 + nt * 4 + i;   // actual key (permuted kf order)
            bool ok = (msel != 0.f) && (key <= qrow);
            float v = ok ? S[j][nt][i] : -1e30f;
            sc[nt][i] = v;
            rmax = fmaxf(rmax, v);
          }
        rmax = fmaxf(rmax, __shfl_xor(rmax, 16));
        rmax = fmaxf(rmax, __shfl_xor(rmax, 32));
        float mn = fmaxf(m_i[j], rmax);
        float av = __builtin_amdgcn_exp2f(m_i[j] - mn);
        m_i[j] = mn;
        float ps[4];
#pragma unroll
        for (int nt = 0; nt < 4; ++nt) {
          float s0 = 0.f;
#pragma unroll
          for (int i = 0; i < 4; ++i) {
            float a = __builtin_amdgcn_exp2f(sc[nt][i] - mn);
            p[nt][i] = a;
            s0 += a;
          }
          ps[nt] = s0;
        }
        float psum = (ps[0] + ps[1]) + (ps[2] + ps[3]);
        psum += __shfl_xor(psum, 16);
        psum += __shfl_xor(psum, 32);
        l_i[j] = l_i[j] * av + psum;
#pragma unroll
        for (int n0 = 0; n0 < 8; ++n0) Oacc[j][n0] *= av;
      }

      // pack P to f16 pairs: word t covers keys Lq*16 + 2t
      unsigned w8[8];
#pragma unroll
      for (int nt = 0; nt < 4; ++nt) {
        w8[2 * nt]     = __builtin_bit_cast(unsigned, __builtin_amdgcn_cvt_pkrtz(p[nt][0], p[nt][1]));
        w8[2 * nt + 1] = __builtin_bit_cast(unsigned, __builtin_amdgcn_cvt_pkrtz(p[nt][2], p[nt][3]));
      }
      // cross-lane exchange: dest (Lm,Lq),kc needs keys kc*32+Lq*8+2u from
      // src lane ((Lq>>1)+2kc)*16+Lm, src word (Lq&1)*4+u.
#pragma unroll
      for (int kc = 0; kc < 2; ++kc) {
        int src = ((Lq >> 1) + 2 * kc) * 16 + Lm;
        u32x4 d;
#pragma unroll
        for (int u = 0; u < 4; ++u) {
          unsigned lo = (unsigned)__shfl((int)w8[u], src, 64);
          unsigned hi = (unsigned)__shfl((int)w8[u + 4], src, 64);
          d[u] = (Lq & 1) ? hi : lo;
        }
        pfr[j][kc] = __builtin_bit_cast(half8, d);
      }
    }

    // ---- fused PV: each V fragment feeds both q-tiles ----
    const half8* lvf = (const half8*)sh_v;
    __builtin_amdgcn_s_setprio(1);
#pragma unroll
    for (int kc = 0; kc < 2; ++kc)
#pragma unroll
      for (int n0 = 0; n0 < 8; ++n0) {
        half8 va = lvf[(n0 * 2 + kc) * 64 + L];
        Oacc[0][n0] = __builtin_amdgcn_mfma_f32_16x16x32_f16(va, pfr[0][kc], Oacc[0][n0], 0, 0, 0);
        Oacc[1][n0] = __builtin_amdgcn_mfma_f32_16x16x32_f16(va, pfr[1][kc], Oacc[1][n0], 0, 0, 0);
      }
    __builtin_amdgcn_s_setprio(0);

    if (nxt < 0) break;
    // (B) V reads retired block-wide; K(nxt) landed everywhere; vreg ready.
    asm volatile("s_waitcnt lgkmcnt(0)\n\ts_waitcnt vmcnt(0)\n\ts_barrier" ::: "memory");
    writeV();                          // sh_v <- V(nxt); visible by next bar(A)
    kb = nxt;
  }

#pragma unroll
  for (int j = 0; j < 2; ++j) {
    float inv = 1.f / l_i[j];
    float* orow = out + (long)(t0 + qoff + j * 16 + Lm) * 2048 + h * 128 + Lq * 4;
#pragma unroll
    for (int n0 = 0; n0 < 8; ++n0) {
      f32x4 o = Oacc[j][n0] * inv;
      *(f32x4*)(orow + n0 * 16) = o;
    }
  }
}

extern "C" void kernel_launch(void* const* d_in, const int* in_sizes, int n_in,
                              void* d_out, int out_size, void* d_ws, size_t ws_size,
                              hipStream_t stream) {
  const float* q = (const float*)d_in[0];
  const float* k = (const float*)d_in[1];
  const float* v = (const float*)d_in[2];
  const int* idx = (const int*)d_in[3];
  _Float16* kf = (_Float16*)d_ws;                       // 2048 blk * 12288 f16 = 50.3 MB
  _Float16* vf = kf + (size_t)2048 * 12288;             // 2048 blk * 8192  f16 = 33.6 MB
  float* out = (float*)d_out;
  kv_prep<<<2048, 256, 0, stream>>>(k, v, kf, vf);
  attn_main<<<2048, 128, 0, stream>>>(q, idx, kf, vf, out);
}